// Round 8
// baseline (763.952 us; speedup 1.0000x reference)
//
#include <hip/hip_runtime.h>

// AnchorStore: KL-argmin 1-NN.
//   score[b,k] = sum_d A[k,d]*log A[k,d]  -  sum_d A[k,d]*log Q[b,d]
//   out[b] = label[argmin_k score[b,k]],  K=2048, D=50257, B=256.
//
// Two-phase D-split (ws window [28.04,30.14) MB): per phase, lq_kernel writes
// bf16 log(Q) slice; gemm writes pch deterministic fp32 partials [z][B][K].
// Round-8 core change: pipelined K-loop that never drains vmcnt at barriers —
// 2-deep register prefetch, double-buffered LDS, raw s_barrier preceded by
// lgkmcnt(0) only (loads stay in flight across barriers; compiler's precise
// register-dependency vmcnt waits gate consumption a full step later).

constexpr int K    = 2048;
constexpr int D    = 50257;
constexpr int B    = 256;
constexpr int BM   = 32;
constexpr int BK   = 64;
constexpr int DSPL = 25344;          // phase-0 length (mult of 64)
constexpr int LQS  = 25408;          // lq row stride (mult of 64, >= both DLr)
constexpr int NC   = 8;
constexpr float MARGIN = 4.0f;

typedef __attribute__((ext_vector_type(8))) short bf16x8;
typedef __attribute__((ext_vector_type(4))) float f32x4;
typedef __attribute__((ext_vector_type(8))) unsigned short u16x8;

__device__ inline unsigned short f2bf_rne(float f) {
    union { float f; unsigned u; } v; v.f = f;
    unsigned r = v.u + 0x7FFFu + ((v.u >> 16) & 1u);
    return (unsigned short)(r >> 16);
}

// ---- lq[b][c] = bf16(log(Q[b][aoff+c])) for c<DL, 0 for c in [DL,LQS) ----
__global__ __launch_bounds__(256)
void lq_kernel(const float* __restrict__ q, unsigned short* __restrict__ lq,
               int aoff, int DL)
{
    const int stride = gridDim.x * blockDim.x;
    const int total  = B * (LQS / 8);
    for (int c = blockIdx.x * blockDim.x + threadIdx.x; c < total; c += stride) {
        const int b  = c / (LQS / 8);
        const int o8 = (c % (LQS / 8)) * 8;
        u16x8 w;
#pragma unroll
        for (int j = 0; j < 8; ++j) {
            const int d = o8 + j;
            const float v = (d < DL) ? q[(size_t)b * D + aoff + d] : 1.f; // log(1)=0
            w[j] = f2bf_rne(__logf(v));
        }
        *reinterpret_cast<u16x8*>(&lq[(size_t)b * LQS + o8]) = w;
    }
}

// ---- GEMM: part[z][B][K] (z local to phase), selfp[zoff+z][K] ----
__global__ __launch_bounds__(512, 2)
void gemm_kernel(const float* __restrict__ anchor,
                 const unsigned short* __restrict__ lq,
                 float* __restrict__ part,     // [pch][B][K]
                 float* __restrict__ selfp,    // [2*pch][K]
                 int dc, int DL, int aoff, int zoff)
{
    // XCD-grouped swizzle: contiguous g-range per XCD -> lq z-slice L2-resident.
    const int nb8 = gridDim.x >> 3;
    const int g   = (blockIdx.x & 7) * nb8 + (blockIdx.x >> 3);
    const int z   = g >> 6;
    const int x   = g & 63;

    const int t    = threadIdx.x;
    const int k0   = x * BM;
    const int d0   = z * dc;
    const int DLr  = (DL + 63) & ~63;
    const int dend = min(d0 + dc, DLr);
    const size_t KD = (size_t)K * D;

    // double-buffered LDS: A rows [0,32), Q rows [32,288): 2 x 36 KB
    __shared__ __align__(16) unsigned short lds[2][(BM + B) * 64];

    // A staging: threads 0..255, row = t>>3 (0..31), 8 cols at (t&7)*8
    const int rowA = t >> 3;
    const int cA   = (t & 7) * 8;
    const int ar   = k0 + (rowA & 31);
    const int swA  = (rowA & 7) << 3;
    const bool doA = (t < 256);

    // Q staging: all threads, row = t>>1 (0..255), 32 cols at (t&1)*32
    const int rowQ = t >> 1;
    const int hq   = (t & 1) * 32;
    const int swQ  = (rowQ & 7) << 3;
    const unsigned short* LQrow = lq + (size_t)rowQ * LQS;

    // MFMA: 8 waves, wave tile 32(m) x 32(n)
    const int w    = t >> 6;
    const int lane = t & 63;
    const int wn   = w * 32;
    const int lrow = lane & 15;
    const int kg   = lane >> 4;

    f32x4 acc[2][2];
#pragma unroll
    for (int mt = 0; mt < 2; ++mt)
#pragma unroll
        for (int nt = 0; nt < 2; ++nt)
#pragma unroll
            for (int i = 0; i < 4; ++i) acc[mt][nt][i] = 0.f;

    float selfacc = 0.f;

    // two named register sets (rule #20: static indexing only)
    float wfA0[12]; int phA0 = 0, dbA0 = 0; u16x8 q0[4];
    float wfA1[12]; int phA1 = 0, dbA1 = 0; u16x8 q1[4];

    auto ld4 = [&](size_t fi) -> float4 {
        if (fi > KD - 4) fi = KD - 4;   // clamped vectors are fully-masked slots
        return *reinterpret_cast<const float4*>(anchor + fi);
    };

    auto load_step = [&](int dt, float (&wf)[12], int& ph, int& db, u16x8 (&qr)[4]) {
        if (doA) {
            db = dt + cA;
            const size_t g0 = (size_t)ar * D + aoff + db;
            ph = (int)(g0 & 3);
            const size_t b0 = g0 - ph;
            const float4 v0 = ld4(b0), v1 = ld4(b0 + 4), v2 = ld4(b0 + 8);
            wf[0] = v0.x; wf[1]  = v0.y; wf[2]  = v0.z; wf[3]  = v0.w;
            wf[4] = v1.x; wf[5]  = v1.y; wf[6]  = v1.z; wf[7]  = v1.w;
            wf[8] = v2.x; wf[9]  = v2.y; wf[10] = v2.z; wf[11] = v2.w;
        }
        const int qb = dt + hq;
#pragma unroll
        for (int gg = 0; gg < 4; ++gg)
            qr[gg] = *reinterpret_cast<const u16x8*>(&LQrow[qb + 8 * gg]);
    };

    auto convert_write = [&](unsigned short* L, float (&wf)[12], int ph, int db,
                             u16x8 (&qr)[4]) {
        if (doA) {
            float s9[9], av[8];
#pragma unroll
            for (int j = 0; j < 9; ++j) s9[j] = (ph & 2) ? wf[j + 2] : wf[j];
#pragma unroll
            for (int j = 0; j < 8; ++j) av[j] = (ph & 1) ? s9[j + 1] : s9[j];
            u16x8 abf;
#pragma unroll
            for (int j = 0; j < 8; ++j) {
                float a = (db + j < DL) ? av[j] : 0.f;
                if (a > 0.f) selfacc = fmaf(a, __logf(a), selfacc);
                abf[j] = (short)f2bf_rne(a);
            }
            *reinterpret_cast<u16x8*>(&L[rowA * 64 + (cA ^ swA)]) = abf;
        }
#pragma unroll
        for (int gg = 0; gg < 4; ++gg)
            *reinterpret_cast<u16x8*>(&L[(BM + rowQ) * 64 + ((hq + 8 * gg) ^ swQ)]) = qr[gg];
    };

    auto mfma_phase = [&](const unsigned short* L) {
#pragma unroll
        for (int half = 0; half < 2; ++half) {
            const int dd = half * 32;
            bf16x8 af[2], qf[2];
#pragma unroll
            for (int mt = 0; mt < 2; ++mt) {
                const int r = mt * 16 + lrow;
                const int c = (dd + kg * 8) ^ ((r & 7) << 3);
                af[mt] = *reinterpret_cast<const bf16x8*>(&L[r * 64 + c]);
            }
#pragma unroll
            for (int nt = 0; nt < 2; ++nt) {
                const int r = wn + nt * 16 + lrow;
                const int c = (dd + kg * 8) ^ ((r & 7) << 3);
                qf[nt] = *reinterpret_cast<const bf16x8*>(&L[(BM + r) * 64 + c]);
            }
#pragma unroll
            for (int mt = 0; mt < 2; ++mt)
#pragma unroll
                for (int nt = 0; nt < 2; ++nt)
                    acc[mt][nt] = __builtin_amdgcn_mfma_f32_16x16x32_bf16(
                        af[mt], qf[nt], acc[mt][nt], 0, 0, 0);
        }
    };

    auto soft_barrier = [&]() {   // ds-writes visible; global loads stay in flight
        asm volatile("s_waitcnt lgkmcnt(0)" ::: "memory");
        __builtin_amdgcn_sched_barrier(0);
        __builtin_amdgcn_s_barrier();
        __builtin_amdgcn_sched_barrier(0);
    };

    if (d0 < dend) {
        const int n = (dend - d0) >> 6;   // >=1, uniform within block
        load_step(d0, wfA0, phA0, dbA0, q0);                    // tile 0 -> set0
        if (n > 1) load_step(d0 + BK, wfA1, phA1, dbA1, q1);    // tile 1 -> set1
        convert_write(lds[0], wfA0, phA0, dbA0, q0);
        soft_barrier();
        for (int s = 0; s < n; ++s) {
            if ((s & 1) == 0) {
                // compute buf0/tile s; stage tile s+1 from set1; prefetch s+2 -> set0
                if (s + 2 < n) load_step(d0 + (s + 2) * BK, wfA0, phA0, dbA0, q0);
                __builtin_amdgcn_sched_barrier(0);
                mfma_phase(lds[0]);
                if (s + 1 < n) {
                    convert_write(lds[1], wfA1, phA1, dbA1, q1);
                    soft_barrier();
                }
            } else {
                if (s + 2 < n) load_step(d0 + (s + 2) * BK, wfA1, phA1, dbA1, q1);
                __builtin_amdgcn_sched_barrier(0);
                mfma_phase(lds[1]);
                if (s + 1 < n) {
                    convert_write(lds[0], wfA0, phA0, dbA0, q0);
                    soft_barrier();
                }
            }
        }
    }

    // epilogue (C/D: col=lane&15 -> b, row=(lane>>4)*4+i -> k)
#pragma unroll
    for (int mt = 0; mt < 2; ++mt)
#pragma unroll
        for (int nt = 0; nt < 2; ++nt) {
            const int kk = k0 + mt * 16 + kg * 4;
            const int bb = wn + nt * 16 + lrow;
            *reinterpret_cast<f32x4*>(&part[((size_t)z * B + bb) * K + kk]) = acc[mt][nt];
        }

    // self partials: 8 staging threads per A row (threads < 256 only)
    float s = selfacc;
    s += __shfl_xor(s, 1);
    s += __shfl_xor(s, 2);
    s += __shfl_xor(s, 4);
    if (doA && (t & 7) == 0) selfp[(size_t)(zoff + z) * K + ar] = s;
}

// ---- crossA[i] = sum_z part[z][i] (phase-0 reduction) ----
__global__ __launch_bounds__(256)
void reduce_kernel(const float* __restrict__ part, float* __restrict__ crossA, int pch)
{
    const int i = blockIdx.x * 256 + threadIdx.x;           // f32x4 index
    const f32x4* p4 = reinterpret_cast<const f32x4*>(part);
    f32x4 s = p4[i];
    for (int z = 1; z < pch; ++z) {
        const f32x4 v = p4[(size_t)z * (B * K / 4) + i];
#pragma unroll
        for (int j = 0; j < 4; ++j) s[j] += v[j];
    }
    reinterpret_cast<f32x4*>(crossA)[i] = s;
}

// ---- reduce self partials over 2*pch rows ----
__global__ __launch_bounds__(256)
void selfsum_kernel(const float* __restrict__ selfp, float* __restrict__ selftot, int rows)
{
    const int k = blockIdx.x * 256 + threadIdx.x;
    float s = 0.f;
    for (int z = 0; z < rows; ++z) s += selfp[(size_t)z * K + k];
    selftot[k] = s;
}

// ---- per-query top-NC + rescore-need gap flag ----
__global__ __launch_bounds__(256)
void topk_kernel(const float* __restrict__ crossA, const float* __restrict__ part,
                 const float* __restrict__ selftot,
                 int* __restrict__ cand, int* __restrict__ need, int pch)
{
    const int b = blockIdx.x, t = threadIdx.x;
    float v[8];
#pragma unroll
    for (int i = 0; i < 8; ++i) {
        const int k = i * 256 + t;
        float cv = crossA[(size_t)b * K + k];
        for (int z = 0; z < pch; ++z) cv += part[((size_t)z * B + b) * K + k];
        v[i] = selftot[k] - cv;
    }
    __shared__ float sv[256];
    __shared__ int   si[256];
    __shared__ float topv[2];
    for (int r = 0; r < NC; ++r) {
        float bv = 3.4e38f; int bk = K;
#pragma unroll
        for (int i = 0; i < 8; ++i) {
            const int k = i * 256 + t;
            if (v[i] < bv) { bv = v[i]; bk = k; }
        }
        sv[t] = bv; si[t] = bk;
        __syncthreads();
        for (int off = 128; off > 0; off >>= 1) {
            if (t < off) {
                if (sv[t + off] < sv[t] || (sv[t + off] == sv[t] && si[t + off] < si[t])) {
                    sv[t] = sv[t + off]; si[t] = si[t + off];
                }
            }
            __syncthreads();
        }
        const int kwin = si[0];
        if ((kwin & 255) == t) v[kwin >> 8] = 3.4e38f;
        if (t == 0) {
            cand[b * NC + r] = kwin;
            if (r < 2) topv[r] = sv[0];
        }
        __syncthreads();
    }
    if (t == 0) need[b] = (topv[1] - topv[0] < MARGIN) ? 1 : 0;
}

// ---- exact fp64 rescore of flagged queries (D split in halves) ----
__global__ __launch_bounds__(512)
void rescore_kernel(const float* __restrict__ query, const float* __restrict__ anchor,
                    const int* __restrict__ cand, const int* __restrict__ need,
                    double* __restrict__ pp)
{
    const int b = blockIdx.x, h = blockIdx.y, t = threadIdx.x;
    if (!need[b]) return;   // uniform exit before any barrier
    const int dlo = h * 25129;
    const int dhi = min(D, dlo + 25129);
    int ks[NC];
#pragma unroll
    for (int c = 0; c < NC; ++c) ks[c] = cand[b * NC + c];
    const float* qrow = query + (size_t)b * D;

    double a8[NC];
#pragma unroll
    for (int c = 0; c < NC; ++c) a8[c] = 0.0;

    for (int d = dlo + t; d < dhi; d += 512) {
        const double lqv = (double)logf(qrow[d]);
#pragma unroll
        for (int c = 0; c < NC; ++c)
            a8[c] = fma((double)anchor[(size_t)ks[c] * D + d], lqv, a8[c]);
    }

    __shared__ double red[512];
    for (int c = 0; c < NC; ++c) {
        red[t] = a8[c];
        __syncthreads();
        for (int off = 256; off > 0; off >>= 1) {
            if (t < off) red[t] += red[t + off];
            __syncthreads();
        }
        if (t == 0) pp[((size_t)b * 2 + h) * NC + c] = red[0];
        __syncthreads();
    }
}

// ---- final decision + label gather ----
__global__ __launch_bounds__(256)
void final_kernel(const double* __restrict__ pp, const float* __restrict__ selftot,
                  const int* __restrict__ cand, const int* __restrict__ need,
                  const int* __restrict__ label, int* __restrict__ out)
{
    const int b = threadIdx.x;
    if (!need[b]) { out[b] = label[cand[b * NC]]; return; }
    float best = 3.4e38f; int bk = K;
#pragma unroll
    for (int c = 0; c < NC; ++c) {
        const int k = cand[b * NC + c];
        const double cv = pp[((size_t)b * 2 + 0) * NC + c] + pp[((size_t)b * 2 + 1) * NC + c];
        const float sc = selftot[k] - (float)cv;
        if (sc < best || (sc == best && k < bk)) { best = sc; bk = k; }
    }
    out[b] = label[bk];
}

extern "C" void kernel_launch(void* const* d_in, const int* in_sizes, int n_in,
                              void* d_out, int out_size, void* d_ws, size_t ws_size,
                              hipStream_t stream)
{
    const float* query  = (const float*)d_in[0];   // [B*D]
    const float* anchor = (const float*)d_in[1];   // [K*D]
    const int*   label  = (const int*)d_in[2];     // [K]
    int* out = (int*)d_out;

    size_t cur = 0;
    auto alloc = [&](size_t bytes) -> void* {
        cur = (cur + 255) & ~(size_t)255;
        void* p = (char*)d_ws + cur;
        cur += bytes;
        return p;
    };

    unsigned short* lq      = (unsigned short*)alloc((size_t)B * LQS * 2); // 13.0MB
    float*          crossA  = (float*)alloc((size_t)B * K * 4);            //  2.1MB
    float*          selfp   = (float*)alloc((size_t)12 * K * 4);
    float*          selftot = (float*)alloc((size_t)K * 4);
    int*            cand    = (int*)alloc((size_t)B * NC * 4);
    int*            need    = (int*)alloc((size_t)B * 4);
    double*         pp      = (double*)alloc((size_t)B * 2 * NC * 8);
    const size_t fixed_end  = cur;

    // partials ladder: largest pch in [1,6] that fits
    int pch = 1;
    for (int s = 6; s >= 1; --s) {
        if (fixed_end + (size_t)s * B * K * 4 + 256 <= ws_size) { pch = s; break; }
    }
    float* part = (float*)alloc((size_t)pch * B * K * 4);                  // 12.6MB @6

    const int DL1 = DSPL, DL2 = D - DSPL;            // 25344, 24913
    const int dc1 = ((DL1 + pch - 1) / pch + 63) & ~63;
    const int dc2 = ((DL2 + pch - 1) / pch + 63) & ~63;

    // ---- phase 0: cols [0, DL1) ----
    lq_kernel<<<2048, 256, 0, stream>>>(query, lq, 0, DL1);
    gemm_kernel<<<64 * pch, 512, 0, stream>>>(anchor, lq, part, selfp, dc1, DL1, 0, 0);
    reduce_kernel<<<B * K / 4 / 256, 256, 0, stream>>>(part, crossA, pch);

    // ---- phase 1: cols [DL1, D) ----
    lq_kernel<<<2048, 256, 0, stream>>>(query, lq, DSPL, DL2);
    gemm_kernel<<<64 * pch, 512, 0, stream>>>(anchor, lq, part, selfp, dc2, DL2, DSPL, pch);

    selfsum_kernel<<<K / 256, 256, 0, stream>>>(selfp, selftot, 2 * pch);
    topk_kernel<<<B, 256, 0, stream>>>(crossA, part, selftot, cand, need, pch);
    rescore_kernel<<<dim3(B, 2), 512, 0, stream>>>(query, anchor, cand, need, pp);
    final_kernel<<<1, 256, 0, stream>>>(pp, selftot, cand, need, label, out);
}

// Round 9
// 536.627 us; speedup vs baseline: 1.4236x; 1.4236x over previous
//
#include <hip/hip_runtime.h>

// AnchorStore: KL-argmin 1-NN.
//   score[b,k] = sum_d A[k,d]*log A[k,d]  -  sum_d A[k,d]*log Q[b,d]
//   out[b] = label[argmin_k score[b,k]],  K=2048, D=50257, B=256.
//
// Round-9: barrier-free register-tile GEMM. Cross-round invariant r4/r7/r8:
// LDS-staged barrier-stepped loops cost ~4.4-5.4us/step (10K+ cycles of
// exposed latency; all resident waves stall at the same barrier). Fix: each
// wave independently computes k32 x b256 x D-subrange in registers (128 VGPR
// acc), Q read directly from a chunked bf16 log(Q) buffer lq[d/32][b][32]
// (1KB fully-coalesced wave-loads, z-slice L2-resident per XCD pair), A read
// once from HBM via unaligned float4 covers. No inner-loop barriers; 8 dsub
// waves per block tree-reduce their accs in LDS once at the end.
// Two-phase D-split keeps lq + fp32 partials inside the proven 28MB ws window.

constexpr int K    = 2048;
constexpr int D    = 50257;
constexpr int B    = 256;
constexpr int DSPL = 25344;          // phase-0 length (mult of 32)
constexpr int NC   = 8;
constexpr float MARGIN = 4.0f;

typedef __attribute__((ext_vector_type(8))) short bf16x8;
typedef __attribute__((ext_vector_type(4))) float f32x4;
typedef __attribute__((ext_vector_type(8))) unsigned short u16x8;

__device__ inline unsigned short f2bf_rne(float f) {
    union { float f; unsigned u; } v; v.f = f;
    unsigned r = v.u + 0x7FFFu + ((v.u >> 16) & 1u);
    return (unsigned short)(r >> 16);
}

// ---- lq[ch][b][32] = bf16(log(Q[b][aoff + ch*32 + c])), zero-padded past DL ----
__global__ __launch_bounds__(256)
void lq_kernel(const float* __restrict__ q, unsigned short* __restrict__ lq,
               int aoff, int DL, int nch)
{
    const int stride = gridDim.x * blockDim.x;
    const int total  = nch * B * 4;                  // 4 subs of 8 elems
    for (int c = blockIdx.x * blockDim.x + threadIdx.x; c < total; c += stride) {
        const int sub = c & 3;
        const int b   = (c >> 2) & 255;
        const int ch  = c >> 10;
        const int d0  = ch * 32 + sub * 8;
        u16x8 w;
#pragma unroll
        for (int j = 0; j < 8; ++j) {
            const int d = d0 + j;
            const float v = (d < DL) ? q[(size_t)b * D + aoff + d] : 1.f; // log(1)=0
            w[j] = f2bf_rne(__logf(v));
        }
        *reinterpret_cast<u16x8*>(&lq[((size_t)ch * B + b) * 32 + sub * 8]) = w;
    }
}

// ---- GEMM: part[z][B][K], selfp[zoff+z][K]; 8 waves = 8 D-subranges ----
__global__ __launch_bounds__(512)
void gemm_kernel(const float* __restrict__ anchor,
                 const unsigned short* __restrict__ lq,
                 float* __restrict__ part,     // [pch][B][K]
                 float* __restrict__ selfp,    // [2*pch][K]
                 int dc, int DL, int DCAP, int aoff, int zoff)
{
    // swizzle: XCD x hosts g in [x*nb8, (x+1)*nb8) -> one z per XCD pair (pch=4)
    const int nb8 = gridDim.x >> 3;
    const int g   = (blockIdx.x & 7) * nb8 + (blockIdx.x >> 3);
    const int z   = g >> 6;                       // 64 k-tiles per z
    const int kt  = g & 63;
    const int k0  = kt * 32;

    const int t    = threadIdx.x;
    const int wid  = t >> 6;                      // 0..7 = D-subrange
    const int lane = t & 63;
    const int lr   = lane & 15;                   // A-row / Q-b within tile
    const int lg   = lane >> 4;                   // 0..3 d-group

    // wave's D-subrange within z
    const int zd0 = z * dc;
    const int zd1 = min(zd0 + dc, DCAP);
    const int wd  = ((dc / 8) + 31) & ~31;
    const int d0  = zd0 + wid * wd;
    const int d1  = min(d0 + wd, zd1);

    const size_t KDm4 = (size_t)K * D - 4;

    f32x4 acc0[16], acc1[16];
#pragma unroll
    for (int j = 0; j < 16; ++j)
#pragma unroll
        for (int i = 0; i < 4; ++i) { acc0[j][i] = 0.f; acc1[j][i] = 0.f; }

    float sacc0 = 0.f, sacc1 = 0.f;

    if (d0 < d1) {
        const int ar0 = k0 + lr;
        const int ar1 = ar0 + 16;
        const size_t gA0 = (size_t)ar0 * D + aoff + d0 + lg * 8;
        const size_t gA1 = (size_t)ar1 * D + aoff + d0 + lg * 8;
        const int ph0 = (int)(gA0 & 3);
        const int ph1 = (int)(gA1 & 3);
        size_t iA0 = gA0 - ph0;
        size_t iA1 = gA1 - ph1;

        // lq per-lane base (ushort units): chunk*8192 + b-row*32 + lg*8
        const unsigned short* qp =
            lq + ((size_t)(d0 >> 5) * (B * 32) + (size_t)lr * 32 + lg * 8);

        auto ld4 = [&](size_t fi) -> float4 {
            if (fi > KDm4) fi = KDm4;             // clamped slots are masked below
            return *reinterpret_cast<const float4*>(anchor + fi);
        };

        for (int dd = d0; dd < d1; dd += 32) {
            const int dbase = dd + lg * 8;        // phase-local col of elem 0
            // ---- A row 0: cover, select, mask, self, bf16 ----
            bf16x8 af0, af1;
            {
                const float4 v0 = ld4(iA0), v1 = ld4(iA0 + 4), v2 = ld4(iA0 + 8);
                float wf[12] = {v0.x, v0.y, v0.z, v0.w, v1.x, v1.y, v1.z, v1.w,
                                v2.x, v2.y, v2.z, v2.w};
                float s9[9];
#pragma unroll
                for (int j = 0; j < 9; ++j) s9[j] = (ph0 & 2) ? wf[j + 2] : wf[j];
#pragma unroll
                for (int j = 0; j < 8; ++j) {
                    float a = (ph0 & 1) ? s9[j + 1] : s9[j];
                    a = (dbase + j < DL) ? a : 0.f;
                    if (a > 0.f) sacc0 = fmaf(a, __logf(a), sacc0);
                    af0[j] = (short)f2bf_rne(a);
                }
                iA0 += 32;
            }
            {
                const float4 v0 = ld4(iA1), v1 = ld4(iA1 + 4), v2 = ld4(iA1 + 8);
                float wf[12] = {v0.x, v0.y, v0.z, v0.w, v1.x, v1.y, v1.z, v1.w,
                                v2.x, v2.y, v2.z, v2.w};
                float s9[9];
#pragma unroll
                for (int j = 0; j < 9; ++j) s9[j] = (ph1 & 2) ? wf[j + 2] : wf[j];
#pragma unroll
                for (int j = 0; j < 8; ++j) {
                    float a = (ph1 & 1) ? s9[j + 1] : s9[j];
                    a = (dbase + j < DL) ? a : 0.f;
                    if (a > 0.f) sacc1 = fmaf(a, __logf(a), sacc1);
                    af1[j] = (short)f2bf_rne(a);
                }
                iA1 += 32;
            }
            // ---- Q frags + MFMA, two half-batches of 8 b-tiles ----
            {
                bf16x8 qf[8];
#pragma unroll
                for (int j = 0; j < 8; ++j)
                    qf[j] = *reinterpret_cast<const bf16x8*>(qp + j * 512);
#pragma unroll
                for (int j = 0; j < 8; ++j) {
                    acc0[j] = __builtin_amdgcn_mfma_f32_16x16x32_bf16(af0, qf[j], acc0[j], 0, 0, 0);
                    acc1[j] = __builtin_amdgcn_mfma_f32_16x16x32_bf16(af1, qf[j], acc1[j], 0, 0, 0);
                }
#pragma unroll
                for (int j = 0; j < 8; ++j)
                    qf[j] = *reinterpret_cast<const bf16x8*>(qp + (8 + j) * 512);
#pragma unroll
                for (int j = 0; j < 8; ++j) {
                    acc0[8 + j] = __builtin_amdgcn_mfma_f32_16x16x32_bf16(af0, qf[j], acc0[8 + j], 0, 0, 0);
                    acc1[8 + j] = __builtin_amdgcn_mfma_f32_16x16x32_bf16(af1, qf[j], acc1[8 + j], 0, 0, 0);
                }
            }
            qp += (size_t)B * 32;                 // next 32-chunk
        }
    }

    // ---- in-wave self reduce across lg groups -> lanes 0..15 hold row sums ----
    sacc0 += __shfl_xor(sacc0, 16); sacc0 += __shfl_xor(sacc0, 32);
    sacc1 += __shfl_xor(sacc1, 16); sacc1 += __shfl_xor(sacc1, 32);

    // ---- block-level reduction: 4 LDS regions [256][36] f32 + self scratch ----
    __shared__ __align__(16) float red[4][256 * 36];    // 147,456 B
    __shared__ float sred[8][32];

    if (lane < 16) { sred[wid][lr] = sacc0; sred[wid][16 + lr] = sacc1; }

    const int rbase = wid & 3;
    if (wid < 4) {
#pragma unroll
        for (int bt = 0; bt < 16; ++bt) {
            float* p0 = &red[rbase][(bt * 16 + lr) * 36 + lg * 4];
            *reinterpret_cast<f32x4*>(p0)      = acc0[bt];
            *reinterpret_cast<f32x4*>(p0 + 16) = acc1[bt];
        }
    }
    __syncthreads();
    if (wid >= 4) {
#pragma unroll
        for (int bt = 0; bt < 16; ++bt) {
            float* p0 = &red[rbase][(bt * 16 + lr) * 36 + lg * 4];
            f32x4 v0 = *reinterpret_cast<f32x4*>(p0);
            f32x4 v1 = *reinterpret_cast<f32x4*>(p0 + 16);
#pragma unroll
            for (int i = 0; i < 4; ++i) { v0[i] += acc0[bt][i]; v1[i] += acc1[bt][i]; }
            *reinterpret_cast<f32x4*>(p0)      = v0;
            *reinterpret_cast<f32x4*>(p0 + 16) = v1;
        }
    }
    __syncthreads();
    for (int i = t; i < 256 * 36; i += 512) {
        red[0][i] += red[2][i];
        red[1][i] += red[3][i];
    }
    __syncthreads();
    for (int i = t; i < 256 * 36; i += 512) red[0][i] += red[1][i];
    if (t < 32) {                               // self over 8 waves (sred ready)
        float s = 0.f;
#pragma unroll
        for (int w8 = 0; w8 < 8; ++w8) s += sred[w8][t];
        selfp[(size_t)(zoff + z) * K + k0 + t] = s;
    }
    __syncthreads();
    for (int i = t; i < 2048; i += 512) {       // 256b x 8 f32x4 = k32
        const int b  = i >> 3;
        const int kq = i & 7;
        const f32x4 v = *reinterpret_cast<f32x4*>(&red[0][b * 36 + kq * 4]);
        *reinterpret_cast<f32x4*>(&part[((size_t)z * B + b) * K + k0 + kq * 4]) = v;
    }
}

// ---- crossA[i] = sum_z part[z][i] (phase-0 fold) ----
__global__ __launch_bounds__(256)
void reduce_kernel(const float* __restrict__ part, float* __restrict__ crossA, int pch)
{
    const int i = blockIdx.x * 256 + threadIdx.x;
    const f32x4* p4 = reinterpret_cast<const f32x4*>(part);
    f32x4 s = p4[i];
    for (int z = 1; z < pch; ++z) {
        const f32x4 v = p4[(size_t)z * (B * K / 4) + i];
#pragma unroll
        for (int j = 0; j < 4; ++j) s[j] += v[j];
    }
    reinterpret_cast<f32x4*>(crossA)[i] = s;
}

// ---- reduce self partials over 2*pch rows ----
__global__ __launch_bounds__(256)
void selfsum_kernel(const float* __restrict__ selfp, float* __restrict__ selftot, int rows)
{
    const int k = blockIdx.x * 256 + threadIdx.x;
    float s = 0.f;
    for (int z = 0; z < rows; ++z) s += selfp[(size_t)z * K + k];
    selftot[k] = s;
}

// ---- per-query top-NC + rescore-need gap flag ----
__global__ __launch_bounds__(256)
void topk_kernel(const float* __restrict__ crossA, const float* __restrict__ part,
                 const float* __restrict__ selftot,
                 int* __restrict__ cand, int* __restrict__ need, int pch)
{
    const int b = blockIdx.x, t = threadIdx.x;
    float v[8];
#pragma unroll
    for (int i = 0; i < 8; ++i) {
        const int k = i * 256 + t;
        float cv = crossA[(size_t)b * K + k];
        for (int z = 0; z < pch; ++z) cv += part[((size_t)z * B + b) * K + k];
        v[i] = selftot[k] - cv;
    }
    __shared__ float sv[256];
    __shared__ int   si[256];
    __shared__ float topv[2];
    for (int r = 0; r < NC; ++r) {
        float bv = 3.4e38f; int bk = K;
#pragma unroll
        for (int i = 0; i < 8; ++i) {
            const int k = i * 256 + t;
            if (v[i] < bv) { bv = v[i]; bk = k; }
        }
        sv[t] = bv; si[t] = bk;
        __syncthreads();
        for (int off = 128; off > 0; off >>= 1) {
            if (t < off) {
                if (sv[t + off] < sv[t] || (sv[t + off] == sv[t] && si[t + off] < si[t])) {
                    sv[t] = sv[t + off]; si[t] = si[t + off];
                }
            }
            __syncthreads();
        }
        const int kwin = si[0];
        if ((kwin & 255) == t) v[kwin >> 8] = 3.4e38f;
        if (t == 0) {
            cand[b * NC + r] = kwin;
            if (r < 2) topv[r] = sv[0];
        }
        __syncthreads();
    }
    if (t == 0) need[b] = (topv[1] - topv[0] < MARGIN) ? 1 : 0;
}

// ---- exact fp64 rescore of flagged queries (D split in halves) ----
__global__ __launch_bounds__(512)
void rescore_kernel(const float* __restrict__ query, const float* __restrict__ anchor,
                    const int* __restrict__ cand, const int* __restrict__ need,
                    double* __restrict__ pp)
{
    const int b = blockIdx.x, h = blockIdx.y, t = threadIdx.x;
    if (!need[b]) return;   // uniform exit before any barrier
    const int dlo = h * 25129;
    const int dhi = min(D, dlo + 25129);
    int ks[NC];
#pragma unroll
    for (int c = 0; c < NC; ++c) ks[c] = cand[b * NC + c];
    const float* qrow = query + (size_t)b * D;

    double a8[NC];
#pragma unroll
    for (int c = 0; c < NC; ++c) a8[c] = 0.0;

    for (int d = dlo + t; d < dhi; d += 512) {
        const double lqv = (double)logf(qrow[d]);
#pragma unroll
        for (int c = 0; c < NC; ++c)
            a8[c] = fma((double)anchor[(size_t)ks[c] * D + d], lqv, a8[c]);
    }

    __shared__ double red[512];
    for (int c = 0; c < NC; ++c) {
        red[t] = a8[c];
        __syncthreads();
        for (int off = 256; off > 0; off >>= 1) {
            if (t < off) red[t] += red[t + off];
            __syncthreads();
        }
        if (t == 0) pp[((size_t)b * 2 + h) * NC + c] = red[0];
        __syncthreads();
    }
}

// ---- final decision + label gather ----
__global__ __launch_bounds__(256)
void final_kernel(const double* __restrict__ pp, const float* __restrict__ selftot,
                  const int* __restrict__ cand, const int* __restrict__ need,
                  const int* __restrict__ label, int* __restrict__ out)
{
    const int b = threadIdx.x;
    if (!need[b]) { out[b] = label[cand[b * NC]]; return; }
    float best = 3.4e38f; int bk = K;
#pragma unroll
    for (int c = 0; c < NC; ++c) {
        const int k = cand[b * NC + c];
        const double cv = pp[((size_t)b * 2 + 0) * NC + c] + pp[((size_t)b * 2 + 1) * NC + c];
        const float sc = selftot[k] - (float)cv;
        if (sc < best || (sc == best && k < bk)) { best = sc; bk = k; }
    }
    out[b] = label[bk];
}

extern "C" void kernel_launch(void* const* d_in, const int* in_sizes, int n_in,
                              void* d_out, int out_size, void* d_ws, size_t ws_size,
                              hipStream_t stream)
{
    const float* query  = (const float*)d_in[0];   // [B*D]
    const float* anchor = (const float*)d_in[1];   // [K*D]
    const int*   label  = (const int*)d_in[2];     // [K]
    int* out = (int*)d_out;

    const int DL1 = DSPL;                 // 25344
    const int DL2 = D - DSPL;             // 24913
    const int nch1 = (DL1 + 31) / 32;     // 792
    const int nch2 = (DL2 + 31) / 32;     // 779
    const int nchmax = nch1;

    size_t cur = 0;
    auto alloc = [&](size_t bytes) -> void* {
        cur = (cur + 255) & ~(size_t)255;
        void* p = (char*)d_ws + cur;
        cur += bytes;
        return p;
    };

    unsigned short* lq      = (unsigned short*)alloc((size_t)nchmax * B * 32 * 2); // 13.0MB
    float*          crossA  = (float*)alloc((size_t)B * K * 4);                    //  2.1MB
    float*          selfp   = (float*)alloc((size_t)12 * K * 4);
    float*          selftot = (float*)alloc((size_t)K * 4);
    int*            cand    = (int*)alloc((size_t)B * NC * 4);
    int*            need    = (int*)alloc((size_t)B * 4);
    double*         pp      = (double*)alloc((size_t)B * 2 * NC * 8);
    const size_t fixed_end  = cur;

    // partials ladder: pch in {4,2,1}
    int pch = 1;
    for (int s = 4; s >= 1; s >>= 1) {
        if (fixed_end + (size_t)s * B * K * 4 + 256 <= ws_size) { pch = s; break; }
    }
    float* part = (float*)alloc((size_t)pch * B * K * 4);                          //  8.4MB @4

    const int dc1 = ((DL1 + pch - 1) / pch + 31) & ~31;   // 6336 @pch=4
    const int dc2 = ((DL2 + pch - 1) / pch + 31) & ~31;   // 6240 @pch=4

    // ---- phase 0: cols [0, DL1) ----
    lq_kernel<<<2048, 256, 0, stream>>>(query, lq, 0, DL1, nch1);
    gemm_kernel<<<64 * pch, 512, 0, stream>>>(anchor, lq, part, selfp,
                                              dc1, DL1, nch1 * 32, 0, 0);
    reduce_kernel<<<B * K / 4 / 256, 256, 0, stream>>>(part, crossA, pch);

    // ---- phase 1: cols [DL1, D) ----
    lq_kernel<<<2048, 256, 0, stream>>>(query, lq, DSPL, DL2, nch2);
    gemm_kernel<<<64 * pch, 512, 0, stream>>>(anchor, lq, part, selfp,
                                              dc2, DL2, nch2 * 32, DSPL, pch);

    selfsum_kernel<<<K / 256, 256, 0, stream>>>(selfp, selftot, 2 * pch);
    topk_kernel<<<B, 256, 0, stream>>>(crossA, part, selftot, cand, need, pch);
    rescore_kernel<<<dim3(B, 2), 512, 0, stream>>>(query, anchor, cand, need, pp);
    final_kernel<<<1, 256, 0, stream>>>(pp, selftot, cand, need, label, out);
}